// Round 5
// baseline (12771.219 us; speedup 1.0000x reference)
//
#include <hip/hip_runtime.h>
#include <cstdint>
#include <cmath>

// Problem constants
#define B_    8
#define H_    72
#define W_    72
#define C_    16
#define C3_   48
#define HP_   16
#define HE_   128
#define T_    64
#define NCELL 41472      // B*H*W

// ---------------------------------------------------------------------------
// JAX threefry2x32 (20 rounds, rotation sets {13,15,26,6} and {17,29,16,24})
// ---------------------------------------------------------------------------
__host__ __device__ __forceinline__ void threefry2x32(uint32_t k0, uint32_t k1,
                                                      uint32_t& x0, uint32_t& x1) {
  uint32_t ks2 = k0 ^ k1 ^ 0x1BD11BDAu;
  x0 += k0; x1 += k1;
#define TF_R(r) { x0 += x1; x1 = (x1 << (r)) | (x1 >> (32 - (r))); x1 ^= x0; }
  TF_R(13) TF_R(15) TF_R(26) TF_R(6)
  x0 += k1; x1 += ks2 + 1u;
  TF_R(17) TF_R(29) TF_R(16) TF_R(24)
  x0 += ks2; x1 += k0 + 2u;
  TF_R(13) TF_R(15) TF_R(26) TF_R(6)
  x0 += k0; x1 += k1 + 3u;
  TF_R(17) TF_R(29) TF_R(16) TF_R(24)
  x0 += k1; x1 += ks2 + 4u;
  TF_R(13) TF_R(15) TF_R(26) TF_R(6)
  x0 += ks2; x1 += k0 + 5u;
#undef TF_R
}

// ---------------------------------------------------------------------------
// init: f32 input -> f64 state; un = 1
// ---------------------------------------------------------------------------
__global__ void k_init(const float* __restrict__ xin, double* __restrict__ xA,
                       double* __restrict__ un) {
  int idx = blockIdx.x * 256 + threadIdx.x;
  if (idx < NCELL * C_) xA[idx] = (double)xin[idx];
  if (idx < NCELL) un[idx] = 1.0;
}

// ---------------------------------------------------------------------------
// perceive: x (cell,16) -> perc (cell,48) = [x, sobel1, sobel2], SAME zero pad
// thread = (cell, c)
// ---------------------------------------------------------------------------
__global__ void k_perceive(const double* __restrict__ x, double* __restrict__ perc) {
  int idx = blockIdx.x * 256 + threadIdx.x;   // exact grid: 2592*256 = NCELL*16
  int c = idx & (C_ - 1);
  int cell = idx >> 4;
  int j = cell % W_; int t = cell / W_; int i = t % H_; int b = t / H_;
  double v[3][3];
#pragma unroll
  for (int di = 0; di < 3; di++) {
#pragma unroll
    for (int dj = 0; dj < 3; dj++) {
      int ii = i + di - 1, jj = j + dj - 1;
      bool ok = (ii >= 0 && ii < H_ && jj >= 0 && jj < W_);
      v[di][dj] = ok ? x[(((size_t)(b * H_ + ii) * W_ + jj) << 4) + c] : 0.0;
    }
  }
  // w1_eff = [[-1,-2,-1],[0,0,0],[1,2,1]]/8 ; w2_eff = [[-1,0,1],[-2,0,2],[-1,0,1]]/8
  double dw1 = (-v[0][0] - 2.0 * v[0][1] - v[0][2] + v[2][0] + 2.0 * v[2][1] + v[2][2]) * 0.125;
  double dw2 = (-v[0][0] + v[0][2] - 2.0 * v[1][0] + 2.0 * v[1][2] - v[2][0] + v[2][2]) * 0.125;
  double* p = perc + (size_t)cell * C3_;
  p[c] = v[1][1];
  p[C_ + c] = dw1;
  p[2 * C_ + c] = dw2;
}

// ---------------------------------------------------------------------------
// conv1 3x3 48->16 + ReLU. thread = (cell, oc); weights in LDS
// ---------------------------------------------------------------------------
__global__ void k_conv1(const double* __restrict__ perc, const float* __restrict__ w,
                        const float* __restrict__ bias, double* __restrict__ hbuf) {
  __shared__ float sw[3 * 3 * C3_ * HP_];   // 6912
  __shared__ float sb[HP_];
  for (int t = threadIdx.x; t < 3 * 3 * C3_ * HP_; t += 256) sw[t] = w[t];
  if (threadIdx.x < HP_) sb[threadIdx.x] = bias[threadIdx.x];
  __syncthreads();
  int idx = blockIdx.x * 256 + threadIdx.x;
  int oc = idx & (HP_ - 1);
  int cell = idx >> 4;
  int j = cell % W_; int t = cell / W_; int i = t % H_; int b = t / H_;
  double acc = (double)sb[oc];
  for (int di = 0; di < 3; di++) {
    int ii = i + di - 1; if (ii < 0 || ii >= H_) continue;
    for (int dj = 0; dj < 3; dj++) {
      int jj = j + dj - 1; if (jj < 0 || jj >= W_) continue;
      const double* p = perc + (size_t)((b * H_ + ii) * W_ + jj) * C3_;
      const float* ww = sw + ((di * 3 + dj) * C3_) * HP_ + oc;
#pragma unroll
      for (int k = 0; k < C3_; k++) acc += p[k] * (double)ww[k * HP_];
    }
  }
  hbuf[(size_t)cell * HP_ + oc] = acc > 0.0 ? acc : 0.0;
}

// ---------------------------------------------------------------------------
// conv2 3x3 16->1 + sigmoid -> lam (pure; no bookkeeping)
// thread = cell
// ---------------------------------------------------------------------------
__global__ void k_conv2(const double* __restrict__ hbuf, const float* __restrict__ w2,
                        const float* __restrict__ b2, double* __restrict__ lam) {
  __shared__ float sw[3 * 3 * HP_];   // 144
  if (threadIdx.x < 3 * 3 * HP_) sw[threadIdx.x] = w2[threadIdx.x];
  __syncthreads();
  int cell = blockIdx.x * 256 + threadIdx.x;   // exact: 162*256 = NCELL
  int j = cell % W_; int t = cell / W_; int i = t % H_; int b = t / H_;
  double z = (double)b2[0];
  for (int di = 0; di < 3; di++) {
    int ii = i + di - 1; if (ii < 0 || ii >= H_) continue;
    for (int dj = 0; dj < 3; dj++) {
      int jj = j + dj - 1; if (jj < 0 || jj >= W_) continue;
      const double* hh = hbuf + (size_t)((b * H_ + ii) * W_ + jj) * HP_;
      const float* ww = sw + (di * 3 + dj) * HP_;
#pragma unroll
      for (int ic = 0; ic < HP_; ic++) z += hh[ic] * (double)ww[ic];
    }
  }
  lam[cell] = 1.0 / (1.0 + exp(-z));
}

// ---------------------------------------------------------------------------
// update: dx = relu(perc@fc0+b)@fc1 ; threefry bernoulli with LAGGED lam ;
// xn = x + dx*upd. For n>=1 also emits lam_steps[n-1], p_steps[n-1], un *= (1-lam).
// RNG: jax_threefry_partitionable: (o1,o2) = threefry2x32(key_n, (0, i));
//   bits = o1 ^ o2; uniform mapped as bits/2^32 in f64 (np mirror semantics).
// thread = cell
// ---------------------------------------------------------------------------
__global__ void __launch_bounds__(256)
k_update(const double* __restrict__ x, const double* __restrict__ perc,
         const double* __restrict__ lam, const float* __restrict__ fc0w,
         const float* __restrict__ fc0b, const float* __restrict__ fc1w,
         double* __restrict__ xn, float* __restrict__ out_upd,
         double* __restrict__ un, float* __restrict__ out_lam,
         double* __restrict__ p_buf,
         uint32_t k0, uint32_t k1, int n) {
  __shared__ float s0[C3_ * HE_];   // 6144
  __shared__ float sb[HE_];
  __shared__ float s1[HE_ * C_];    // 2048
  for (int t = threadIdx.x; t < C3_ * HE_; t += 256) s0[t] = fc0w[t];
  for (int t = threadIdx.x; t < HE_; t += 256) sb[t] = fc0b[t];
  for (int t = threadIdx.x; t < HE_ * C_; t += 256) s1[t] = fc1w[t];
  __syncthreads();
  int cell = blockIdx.x * 256 + threadIdx.x;
  double pv[C3_];
#pragma unroll
  for (int k = 0; k < C3_; k++) pv[k] = perc[(size_t)cell * C3_ + k];
  double dx[C_];
#pragma unroll
  for (int c = 0; c < C_; c++) dx[c] = 0.0;
  for (int e = 0; e < HE_; e++) {
    double a = (double)sb[e];
#pragma unroll
    for (int k = 0; k < C3_; k++) a += pv[k] * (double)s0[k * HE_ + e];
    if (a > 0.0) {
#pragma unroll
      for (int c = 0; c < C_; c++) dx[c] += a * (double)s1[e * C_ + c];
    }
  }
  double l = lam[cell];
  // scan-step bookkeeping (uses the SAME lagged lam as the bernoulli below)
  if (n >= 1) {
    size_t o = (size_t)(n - 1) * NCELL + cell;
    out_lam[o] = (float)l;
    double u = un[cell];
    p_buf[o] = u * l + 1e-6;
    un[cell] = u * (1.0 - l);
  }
  // partitionable threefry draw for flat index `cell`: bits = o1 ^ o2
  uint32_t r0 = 0u, r1 = (uint32_t)cell;
  threefry2x32(k0, k1, r0, r1);
  uint32_t bits = r0 ^ r1;
  double uf = (double)bits * 0x1p-32;          // np-mirror uniform: bits / 2^32 (f64)
  double upd = (uf < l) ? 0.0 : 1.0;           // upd = 1 - bernoulli
  out_upd[(size_t)n * NCELL + cell] = (float)upd;
  const double* xc = x + (size_t)cell * C_;
  double* xo = xn + (size_t)cell * C_;
#pragma unroll
  for (int c = 0; c < C_; c++) xo[c] = xc[c] + dx[c] * upd;
}

// ---------------------------------------------------------------------------
// life mask: x_new = xn * (alive(x_old) & alive(xn)); emit x_steps[n]
// thread = cell
// ---------------------------------------------------------------------------
__global__ void k_life(const double* __restrict__ xold, const double* __restrict__ xn,
                       double* __restrict__ xout, float* __restrict__ out_x, int n) {
  int cell = blockIdx.x * 256 + threadIdx.x;
  int j = cell % W_; int t = cell / W_; int i = t % H_; int b = t / H_;
  double mo = -1e300, mn2 = -1e300;
  for (int di = -1; di <= 1; di++) {
    int ii = i + di; if (ii < 0 || ii >= H_) continue;
    for (int dj = -1; dj <= 1; dj++) {
      int jj = j + dj; if (jj < 0 || jj >= W_) continue;
      size_t nb = (size_t)((b * H_ + ii) * W_ + jj) * C_;
      double a0 = xold[nb + 3]; if (a0 > mo) mo = a0;
      double a1 = xn[nb + 3];   if (a1 > mn2) mn2 = a1;
    }
  }
  bool life = (mo > 0.1) && (mn2 > 0.1);
  const double* xi = xn + (size_t)cell * C_;
  double* xo = xout + (size_t)cell * C_;
  float* oo = out_x + (size_t)n * NCELL * C_ + (size_t)cell * C_;
#pragma unroll
  for (int c = 0; c < C_; c++) {
    double v = life ? xi[c] : 0.0;
    xo[c] = v;
    oo[c] = (float)v;
  }
}

// ---------------------------------------------------------------------------
// final emission for scan step 64: lam_steps[63], p_steps[63] from lagged lam
// ---------------------------------------------------------------------------
__global__ void k_emit(const double* __restrict__ lam, const double* __restrict__ un,
                       float* __restrict__ out_lam, double* __restrict__ p_buf) {
  int cell = blockIdx.x * 256 + threadIdx.x;
  double l = lam[cell];
  size_t o = (size_t)(T_ - 1) * NCELL + cell;
  out_lam[o] = (float)l;
  p_buf[o] = un[cell] * l + 1e-6;
}

// ---------------------------------------------------------------------------
// final: p_norm[t] = p[t] / sum_t p[t]
// ---------------------------------------------------------------------------
__global__ void k_pnorm(const double* __restrict__ p_buf, float* __restrict__ out_p) {
  int cell = blockIdx.x * 256 + threadIdx.x;
  double s = 0.0;
  for (int t = 0; t < T_; t++) s += p_buf[(size_t)t * NCELL + cell];
  for (int t = 0; t < T_; t++)
    out_p[(size_t)t * NCELL + cell] = (float)(p_buf[(size_t)t * NCELL + cell] / s);
}

// ---------------------------------------------------------------------------
extern "C" void kernel_launch(void* const* d_in, const int* in_sizes, int n_in,
                              void* d_out, int out_size, void* d_ws, size_t ws_size,
                              hipStream_t stream) {
  const float* xin = (const float*)d_in[0];
  const float* w1  = (const float*)d_in[1];
  const float* b1  = (const float*)d_in[2];
  const float* w2  = (const float*)d_in[3];
  const float* b2  = (const float*)d_in[4];
  const float* f0w = (const float*)d_in[5];
  const float* f0b = (const float*)d_in[6];
  const float* f1w = (const float*)d_in[7];

  float* out     = (float*)d_out;
  float* out_x   = out;                                   // (64, NCELL, 16)
  float* out_p   = out_x + (size_t)T_ * NCELL * C_;       // (64, NCELL)
  float* out_lam = out_p + (size_t)T_ * NCELL;            // (64, NCELL)
  float* out_upd = out_lam + (size_t)T_ * NCELL;          // (64, NCELL)

  // workspace layout (all f64)
  double* ws   = (double*)d_ws;
  double* xA   = ws;                                  // NCELL*16
  double* xB   = xA + (size_t)NCELL * C_;             // NCELL*16
  double* xn   = xB + (size_t)NCELL * C_;             // NCELL*16
  double* perc = xn + (size_t)NCELL * C_;             // NCELL*48
  double* hbuf = perc + (size_t)NCELL * C3_;          // NCELL*16
  double* lamA = hbuf + (size_t)NCELL * HP_;          // NCELL
  double* lamB = lamA + NCELL;                        // NCELL
  double* un   = lamB + NCELL;                        // NCELL
  double* p_buf = un + NCELL;                         // 64*NCELL

  k_init<<<2592, 256, 0, stream>>>(xin, xA, un);

  // --- initial: perc0, lam0 = L(perc(x_init)), update #0 ---
  k_perceive<<<2592, 256, 0, stream>>>(xA, perc);
  k_conv1<<<2592, 256, 0, stream>>>(perc, w1, b1, hbuf);
  k_conv2<<<162, 256, 0, stream>>>(hbuf, w2, b2, lamA);
  {
    uint32_t kx0 = 0u, kx1 = 0u;
    threefry2x32(0u, 42u, kx0, kx1);
    k_update<<<162, 256, 0, stream>>>(xA, perc, lamA, f0w, f0b, f1w,
                                      xn, out_upd, un, out_lam, p_buf, kx0, kx1, 0);
  }
  k_life<<<162, 256, 0, stream>>>(xA, xn, xB, out_x, 0);
  { double* t = xA; xA = xB; xB = t; }

  double* cur = lamA;   // lagged lam entering iteration n
  double* nxt = lamB;

  for (int n = 1; n <= T_ - 1; n++) {
    // fresh lambda from current state (consumed at iteration n+1)
    k_perceive<<<2592, 256, 0, stream>>>(xA, perc);
    k_conv1<<<2592, 256, 0, stream>>>(perc, w1, b1, hbuf);
    k_conv2<<<162, 256, 0, stream>>>(hbuf, w2, b2, nxt);
    // update #n: bernoulli + bookkeeping use LAGGED lam `cur`; dx uses fresh perc
    uint32_t kx0 = 0u, kx1 = (uint32_t)n;
    threefry2x32(0u, 42u, kx0, kx1);
    k_update<<<162, 256, 0, stream>>>(xA, perc, cur, f0w, f0b, f1w,
                                      xn, out_upd, un, out_lam, p_buf, kx0, kx1, n);
    k_life<<<162, 256, 0, stream>>>(xA, xn, xB, out_x, n);
    { double* t = xA; xA = xB; xB = t; }
    { double* t = cur; cur = nxt; nxt = t; }
  }

  // scan step 64: emit lam_steps[63], p_steps[63] from cur = L(perc(x62))
  k_emit<<<162, 256, 0, stream>>>(cur, un, out_lam, p_buf);
  k_pnorm<<<162, 256, 0, stream>>>(p_buf, out_p);
}